// Round 4
// baseline (898.632 us; speedup 1.0000x reference)
//
#include <hip/hip_runtime.h>
#include <math.h>

#define N_NODES 50000
#define N_EDGES 800000
#define IN_F 64
#define OUT_F 32
#define STEPS 20
#define LR 0.1f
#define SLOPE 0.2f

#define SCAN_BLK 256
#define SCAN_NBLK ((N_NODES + SCAN_BLK - 1) / SCAN_BLK)  // 196

// ---------------- CSR build ----------------

__global__ void hist_kernel(const int* __restrict__ dst, int* __restrict__ deg) {
    int e = blockIdx.x * blockDim.x + threadIdx.x;
    if (e < N_EDGES) atomicAdd(&deg[dst[e]], 1);
}

// phase 1: per-block inclusive scan of deg -> row_scan, block totals -> blocksum
__global__ void scan1_kernel(const int* __restrict__ deg, int* __restrict__ row_scan,
                             int* __restrict__ blocksum) {
    __shared__ int wsum[4];
    int tid = threadIdx.x, lane = tid & 63, wid = tid >> 6;
    int i = blockIdx.x * SCAN_BLK + tid;
    int v = (i < N_NODES) ? deg[i] : 0;
    int s = v;
    for (int off = 1; off < 64; off <<= 1) {
        int t = __shfl_up(s, off, 64);
        if (lane >= off) s += t;
    }
    if (lane == 63) wsum[wid] = s;
    __syncthreads();
    if (tid == 0) {
        int a = wsum[0]; wsum[0] = 0;
        int b = wsum[1]; wsum[1] = a; a += b;
        b = wsum[2]; wsum[2] = a; a += b;
        b = wsum[3]; wsum[3] = a; a += b;
        blocksum[blockIdx.x] = a;
    }
    __syncthreads();
    int incl = s + wsum[wid];
    if (i < N_NODES) row_scan[i] = incl;
}

// phase 2: single block, exclusive scan of blocksum in place
__global__ void scan2_kernel(int* __restrict__ blocksum) {
    __shared__ int wsum[4];
    int tid = threadIdx.x, lane = tid & 63, wid = tid >> 6;
    int v = (tid < SCAN_NBLK) ? blocksum[tid] : 0;
    int s = v;
    for (int off = 1; off < 64; off <<= 1) {
        int t = __shfl_up(s, off, 64);
        if (lane >= off) s += t;
    }
    if (lane == 63) wsum[wid] = s;
    __syncthreads();
    if (tid == 0) {
        int a = wsum[0]; wsum[0] = 0;
        int b = wsum[1]; wsum[1] = a; a += b;
        b = wsum[2]; wsum[2] = a; a += b;
        b = wsum[3]; wsum[3] = a; a += b;
    }
    __syncthreads();
    int excl = s - v + wsum[wid];
    if (tid < SCAN_NBLK) blocksum[tid] = excl;
}

// phase 3: add block offsets -> row_start[i+1]; row_start[0]=0
__global__ void scan3_kernel(const int* __restrict__ row_scan, const int* __restrict__ blockoff,
                             int* __restrict__ row_start) {
    int i = blockIdx.x * SCAN_BLK + threadIdx.x;
    if (blockIdx.x == 0 && threadIdx.x == 0) row_start[0] = 0;
    if (i < N_NODES) row_start[i + 1] = row_scan[i] + blockoff[blockIdx.x];
}

// scatter src into CSR slots; record inverse permutation (coalesced write)
__global__ void csr_build_kernel(const int* __restrict__ src, const int* __restrict__ dst,
                                 const int* __restrict__ row_start,
                                 int* __restrict__ cursor, int* __restrict__ csr_src,
                                 int* __restrict__ perm) {
    int e = blockIdx.x * blockDim.x + threadIdx.x;
    if (e < N_EDGES) {
        int d = dst[e];
        int p = atomicAdd(&cursor[d], 1) + row_start[d];
        csr_src[p] = src[e];
        perm[e] = p;
    }
}

// alpha0 in CSR order: 1/deg per row
__global__ void alpha_init_kernel(const int* __restrict__ row_start, float* __restrict__ alpha_csr) {
    int n = blockIdx.x * blockDim.x + threadIdx.x;
    if (n >= N_NODES) return;
    int rs = row_start[n], re = row_start[n + 1];
    float v = 1.0f / ((float)(re - rs) + 1e-8f);
    for (int i = rs; i < re; i++) alpha_csr[i] = v;
}

// transformed = mu_upper @ W^T : thread-per-node, W staged in LDS, mu row in regs
__global__ __launch_bounds__(256) void transform_kernel(const float* __restrict__ mu_upper,
                                                        const float* __restrict__ W,
                                                        float* __restrict__ transformed) {
    __shared__ float4 Ws[OUT_F][IN_F / 4];  // 8 KB
    int tid = threadIdx.x;
    for (int t = tid; t < OUT_F * IN_F / 4; t += 256) ((float4*)Ws)[t] = ((const float4*)W)[t];
    __syncthreads();
    int n = blockIdx.x * 256 + tid;
    if (n >= N_NODES) return;
    float4 row[16];
    const float4* m4 = (const float4*)(mu_upper + n * IN_F);
#pragma unroll
    for (int k = 0; k < 16; k++) row[k] = m4[k];
    float4* outp = (float4*)(transformed + n * OUT_F);
#pragma unroll
    for (int oc = 0; oc < OUT_F / 4; oc++) {
        float4 r;
        float* rp = (float*)&r;
#pragma unroll
        for (int oi = 0; oi < 4; oi++) {
            int o = oc * 4 + oi;
            float acc = 0.f;
#pragma unroll
            for (int k = 0; k < 16; k++) {
                float4 w = Ws[o][k];
                acc += row[k].x * w.x + row[k].y * w.y + row[k].z * w.z + row[k].w * w.w;
            }
            rp[oi] = acc;
        }
        outp[oc] = r;
    }
}

// ---------------- main iteration ----------------
// ONE WAVE PER NODE. lane = eslot(0..7)*8 + c(0..7).
// 8-lane chunk-groups read a src row as 8 contiguous float4 (128B coalesced);
// 8 edges (x2 unroll = 16) in flight per wave. No LDS.
template <bool FINAL>
__global__ __launch_bounds__(256) void stepA_kernel(
        const int* __restrict__ row_start, const int* __restrict__ csr_src,
        const float* __restrict__ alpha_csr, const float* __restrict__ transformed,
        float* __restrict__ mu, float* __restrict__ errors_out,
        const float* __restrict__ a_vec,
        float* __restrict__ s_src, float* __restrict__ s_dst) {
    int n = blockIdx.x * 4 + (threadIdx.x >> 6);
    if (n >= N_NODES) return;
    int lane = threadIdx.x & 63;
    int eslot = lane >> 3, c = lane & 7;
    int rs = row_start[n], re = row_start[n + 1];
    float4 agg = make_float4(0.f, 0.f, 0.f, 0.f);
    for (int base = rs; base < re; base += 16) {
        int j0 = base + eslot;
        int j1 = j0 + 8;
        if (j0 < re) {
            float al = alpha_csr[j0];
            int s = csr_src[j0];
            float4 t = *(const float4*)(transformed + (s << 5) + (c << 2));
            agg.x = fmaf(al, t.x, agg.x);
            agg.y = fmaf(al, t.y, agg.y);
            agg.z = fmaf(al, t.z, agg.z);
            agg.w = fmaf(al, t.w, agg.w);
        }
        if (j1 < re) {
            float al = alpha_csr[j1];
            int s = csr_src[j1];
            float4 t = *(const float4*)(transformed + (s << 5) + (c << 2));
            agg.x = fmaf(al, t.x, agg.x);
            agg.y = fmaf(al, t.y, agg.y);
            agg.z = fmaf(al, t.z, agg.z);
            agg.w = fmaf(al, t.w, agg.w);
        }
    }
    // reduce over eslot (lane bits 3..5)
#pragma unroll
    for (int off = 8; off <= 32; off <<= 1) {
        agg.x += __shfl_xor(agg.x, off, 64);
        agg.y += __shfl_xor(agg.y, off, 64);
        agg.z += __shfl_xor(agg.z, off, 64);
        agg.w += __shfl_xor(agg.w, off, 64);
    }
    if (eslot == 0) {  // lanes 0..7 hold chunks 0..7
        float4* mup = (float4*)(mu + (n << 5) + (c << 2));
        float4 muv = *mup;
        float4 err;
        err.x = muv.x - fmaxf(agg.x, 0.f);
        err.y = muv.y - fmaxf(agg.y, 0.f);
        err.z = muv.z - fmaxf(agg.z, 0.f);
        err.w = muv.w - fmaxf(agg.w, 0.f);
        if (FINAL) {
            *(float4*)(errors_out + (n << 5) + (c << 2)) = err;
        } else {
            float4 nm;
            nm.x = fmaf(-LR, err.x, muv.x);
            nm.y = fmaf(-LR, err.y, muv.y);
            nm.z = fmaf(-LR, err.z, muv.z);
            nm.w = fmaf(-LR, err.w, muv.w);
            *mup = nm;
            float4 as = *(const float4*)(a_vec + (c << 2));
            float4 ad = *(const float4*)(a_vec + OUT_F + (c << 2));
            float v1 = err.x * as.x + err.y * as.y + err.z * as.z + err.w * as.w;
            float v2 = err.x * ad.x + err.y * ad.y + err.z * ad.z + err.w * ad.w;
#pragma unroll
            for (int off = 1; off <= 4; off <<= 1) {  // stays within lanes 0..7
                v1 += __shfl_xor(v1, off, 64);
                v2 += __shfl_xor(v2, off, 64);
            }
            if (c == 0) { s_src[n] = v1; s_dst[n] = v2; }
        }
    }
}

// 16 lanes per node: leaky-relu scores + segment softmax, alpha in CSR order.
__global__ __launch_bounds__(256) void stepB_kernel(
        const int* __restrict__ row_start, const int* __restrict__ csr_src,
        const float* __restrict__ s_src, const float* __restrict__ s_dst,
        float* __restrict__ alpha_csr) {
    int g = threadIdx.x >> 4;
    int lane = threadIdx.x & 15;
    int n = blockIdx.x * 16 + g;
    if (n >= N_NODES) return;
    int rs = row_start[n], re = row_start[n + 1];
    int cnt = re - rs;
    if (cnt <= 0) return;
    float sd = s_dst[n];
    int nch = (cnt + 15) >> 4;
    float b0 = -INFINITY, b1 = -INFINITY;
    float m = -INFINITY;
    for (int c = 0; c < nch; c++) {
        int idx = rs + (c << 4) + lane;
        float sc = -INFINITY;
        if (idx < re) {
            float v = s_src[csr_src[idx]] + sd;
            sc = v > 0.0f ? v : SLOPE * v;
        }
        if (c == 0) b0 = sc; else if (c == 1) b1 = sc;
        m = fmaxf(m, sc);
    }
    for (int off = 8; off >= 1; off >>= 1) m = fmaxf(m, __shfl_xor(m, off, 16));
    float sum = 0.0f;
    for (int c = 0; c < nch; c++) {
        int idx = rs + (c << 4) + lane;
        float sc;
        if (c == 0) sc = b0;
        else if (c == 1) sc = b1;
        else {
            sc = -INFINITY;
            if (idx < re) {
                float v = s_src[csr_src[idx]] + sd;
                sc = v > 0.0f ? v : SLOPE * v;
            }
        }
        float e = (idx < re) ? __expf(sc - m) : 0.0f;
        if (c == 0) b0 = e; else if (c == 1) b1 = e;
        sum += e;
    }
    for (int off = 8; off >= 1; off >>= 1) sum += __shfl_xor(sum, off, 16);
    float inv = 1.0f / (sum + 1e-8f);
    for (int c = 0; c < nch; c++) {
        int idx = rs + (c << 4) + lane;
        float e;
        if (c == 0) e = b0;
        else if (c == 1) e = b1;
        else {
            float sc = -INFINITY;
            if (idx < re) {
                float v = s_src[csr_src[idx]] + sd;
                sc = v > 0.0f ? v : SLOPE * v;
            }
            e = (idx < re) ? __expf(sc - m) : 0.0f;
        }
        if (idx < re) alpha_csr[idx] = e * inv;
    }
}

// final: original-order alpha via gather through inverse permutation (no scatter)
__global__ void gather_alpha_kernel(const int* __restrict__ perm,
                                    const float* __restrict__ alpha_csr,
                                    float* __restrict__ alpha_out) {
    int e = blockIdx.x * blockDim.x + threadIdx.x;
    if (e < N_EDGES) alpha_out[e] = alpha_csr[perm[e]];
}

extern "C" void kernel_launch(void* const* d_in, const int* in_sizes, int n_in,
                              void* d_out, int out_size, void* d_ws, size_t ws_size,
                              hipStream_t stream) {
    const float* mu_upper = (const float*)d_in[0];
    const float* W        = (const float*)d_in[1];
    const float* a_vec    = (const float*)d_in[2];
    const int*   edge_idx = (const int*)d_in[3];
    const int*   src = edge_idx;
    const int*   dst = edge_idx + N_EDGES;

    float* out = (float*)d_out;
    float* mu         = out;                        // N*32
    float* errors_out = out + N_NODES * OUT_F;      // N*32
    float* alpha_out  = out + 2 * N_NODES * OUT_F;  // E

    char* ws = (char*)d_ws;
    int*   deg        = (int*)(ws + 0);             // 200000
    int*   row_scan   = (int*)(ws + 200000);        // 200000
    int*   row_start  = (int*)(ws + 400000);        // 200004
    int*   blocksum   = (int*)(ws + 600016);        // 1024
    int*   cursor     = (int*)(ws + 601040);        // 200000
    float* s_src      = (float*)(ws + 801040);      // 200000
    float* s_dst      = (float*)(ws + 1001040);     // 200000
    int*   csr_src    = (int*)(ws + 1201040);       // 3200000
    int*   perm       = (int*)(ws + 4401040);       // 3200000
    float* alpha_csr  = (float*)(ws + 7601040);     // 3200000
    float* transformed= (float*)(ws + 10801040);    // 6400000  (end ~17.2 MB)

    hipMemsetAsync(deg, 0, N_NODES * sizeof(int), stream);
    hipMemsetAsync(cursor, 0, N_NODES * sizeof(int), stream);
    hipMemsetAsync(mu, 0, N_NODES * OUT_F * sizeof(float), stream);

    hist_kernel<<<(N_EDGES + 255) / 256, 256, 0, stream>>>(dst, deg);
    scan1_kernel<<<SCAN_NBLK, SCAN_BLK, 0, stream>>>(deg, row_scan, blocksum);
    scan2_kernel<<<1, 256, 0, stream>>>(blocksum);
    scan3_kernel<<<SCAN_NBLK, SCAN_BLK, 0, stream>>>(row_scan, blocksum, row_start);
    csr_build_kernel<<<(N_EDGES + 255) / 256, 256, 0, stream>>>(src, dst, row_start, cursor,
                                                                csr_src, perm);
    alpha_init_kernel<<<(N_NODES + 255) / 256, 256, 0, stream>>>(row_start, alpha_csr);
    transform_kernel<<<(N_NODES + 255) / 256, 256, 0, stream>>>(mu_upper, W, transformed);

    for (int it = 0; it < STEPS; it++) {
        stepA_kernel<false><<<(N_NODES + 3) / 4, 256, 0, stream>>>(
            row_start, csr_src, alpha_csr, transformed, mu, errors_out, a_vec, s_src, s_dst);
        stepB_kernel<<<(N_NODES + 15) / 16, 256, 0, stream>>>(row_start, csr_src, s_src, s_dst,
                                                              alpha_csr);
    }
    stepA_kernel<true><<<(N_NODES + 3) / 4, 256, 0, stream>>>(
        row_start, csr_src, alpha_csr, transformed, mu, errors_out, a_vec, s_src, s_dst);
    gather_alpha_kernel<<<(N_EDGES + 255) / 256, 256, 0, stream>>>(perm, alpha_csr, alpha_out);
}

// Round 5
// 816.123 us; speedup vs baseline: 1.1011x; 1.1011x over previous
//
#include <hip/hip_runtime.h>
#include <math.h>

#define N_NODES 50000
#define N_EDGES 800000
#define IN_F 64
#define OUT_F 32
#define STEPS 20
#define LR 0.1f
#define SLOPE 0.2f

#define SCAN_BLK 256
#define SCAN_NBLK ((N_NODES + SCAN_BLK - 1) / SCAN_BLK)  // 196

// ---------------- CSR build ----------------

__global__ void hist_kernel(const int* __restrict__ dst, int* __restrict__ deg) {
    int e = blockIdx.x * blockDim.x + threadIdx.x;
    if (e < N_EDGES) atomicAdd(&deg[dst[e]], 1);
}

__global__ void scan1_kernel(const int* __restrict__ deg, int* __restrict__ row_scan,
                             int* __restrict__ blocksum) {
    __shared__ int wsum[4];
    int tid = threadIdx.x, lane = tid & 63, wid = tid >> 6;
    int i = blockIdx.x * SCAN_BLK + tid;
    int v = (i < N_NODES) ? deg[i] : 0;
    int s = v;
    for (int off = 1; off < 64; off <<= 1) {
        int t = __shfl_up(s, off, 64);
        if (lane >= off) s += t;
    }
    if (lane == 63) wsum[wid] = s;
    __syncthreads();
    if (tid == 0) {
        int a = wsum[0]; wsum[0] = 0;
        int b = wsum[1]; wsum[1] = a; a += b;
        b = wsum[2]; wsum[2] = a; a += b;
        b = wsum[3]; wsum[3] = a; a += b;
        blocksum[blockIdx.x] = a;
    }
    __syncthreads();
    int incl = s + wsum[wid];
    if (i < N_NODES) row_scan[i] = incl;
}

__global__ void scan2_kernel(int* __restrict__ blocksum) {
    __shared__ int wsum[4];
    int tid = threadIdx.x, lane = tid & 63, wid = tid >> 6;
    int v = (tid < SCAN_NBLK) ? blocksum[tid] : 0;
    int s = v;
    for (int off = 1; off < 64; off <<= 1) {
        int t = __shfl_up(s, off, 64);
        if (lane >= off) s += t;
    }
    if (lane == 63) wsum[wid] = s;
    __syncthreads();
    if (tid == 0) {
        int a = wsum[0]; wsum[0] = 0;
        int b = wsum[1]; wsum[1] = a; a += b;
        b = wsum[2]; wsum[2] = a; a += b;
        b = wsum[3]; wsum[3] = a; a += b;
    }
    __syncthreads();
    int excl = s - v + wsum[wid];
    if (tid < SCAN_NBLK) blocksum[tid] = excl;
}

__global__ void scan3_kernel(const int* __restrict__ row_scan, const int* __restrict__ blockoff,
                             int* __restrict__ row_start) {
    int i = blockIdx.x * SCAN_BLK + threadIdx.x;
    if (blockIdx.x == 0 && threadIdx.x == 0) row_start[0] = 0;
    if (i < N_NODES) row_start[i + 1] = row_scan[i] + blockoff[blockIdx.x];
}

__global__ void csr_build_kernel(const int* __restrict__ src, const int* __restrict__ dst,
                                 const int* __restrict__ row_start,
                                 int* __restrict__ cursor, int* __restrict__ csr_src,
                                 int* __restrict__ perm) {
    int e = blockIdx.x * blockDim.x + threadIdx.x;
    if (e < N_EDGES) {
        int d = dst[e];
        int p = atomicAdd(&cursor[d], 1) + row_start[d];
        csr_src[p] = src[e];
        perm[e] = p;
    }
}

// transformed = mu_upper @ W^T : thread-per-node, W staged in LDS
__global__ __launch_bounds__(256) void transform_kernel(const float* __restrict__ mu_upper,
                                                        const float* __restrict__ W,
                                                        float* __restrict__ transformed) {
    __shared__ float4 Ws[OUT_F][IN_F / 4];  // 8 KB
    int tid = threadIdx.x;
    for (int t = tid; t < OUT_F * IN_F / 4; t += 256) ((float4*)Ws)[t] = ((const float4*)W)[t];
    __syncthreads();
    int n = blockIdx.x * 256 + tid;
    if (n >= N_NODES) return;
    float4 row[16];
    const float4* m4 = (const float4*)(mu_upper + n * IN_F);
#pragma unroll
    for (int k = 0; k < 16; k++) row[k] = m4[k];
    float4* outp = (float4*)(transformed + n * OUT_F);
#pragma unroll
    for (int oc = 0; oc < OUT_F / 4; oc++) {
        float4 r;
        float* rp = (float*)&r;
#pragma unroll
        for (int oi = 0; oi < 4; oi++) {
            int o = oc * 4 + oi;
            float acc = 0.f;
#pragma unroll
            for (int k = 0; k < 16; k++) {
                float4 w = Ws[o][k];
                acc += row[k].x * w.x + row[k].y * w.y + row[k].z * w.z + row[k].w * w.w;
            }
            rp[oi] = acc;
        }
        outp[oc] = r;
    }
}

// ---------------- main iteration (fused) ----------------
// ONE WAVE PER NODE. lane = eslot(0..7)*8 + c(0..7).
// First kernel: top_down with uniform alpha0 = 1/(deg+eps); mu_prev = 0.
__global__ __launch_bounds__(256) void firstA_kernel(
        const int* __restrict__ row_start, const int* __restrict__ csr_src,
        const float* __restrict__ transformed,
        float* __restrict__ mu, const float* __restrict__ a_vec,
        float* __restrict__ s_out_src, float* __restrict__ s_out_dst) {
    int n = blockIdx.x * 4 + (threadIdx.x >> 6);
    if (n >= N_NODES) return;
    int lane = threadIdx.x & 63;
    int eslot = lane >> 3, c = lane & 7;
    int rs = row_start[n], re = row_start[n + 1];
    int cnt = re - rs;
    int idx = rs + lane;
    int my_src = (idx < re) ? csr_src[idx] : 0;
    float4 agg = make_float4(0.f, 0.f, 0.f, 0.f);
#pragma unroll
    for (int k = 0; k < 8; k++) {
        int sl = eslot + 8 * k;
        int sj = __shfl(my_src, sl, 64);
        if (rs + sl < re) {
            float4 t = *(const float4*)(transformed + (sj << 5) + (c << 2));
            agg.x += t.x; agg.y += t.y; agg.z += t.z; agg.w += t.w;
        }
    }
    for (int j = rs + 64 + eslot; j < re; j += 8) {  // deg>64 tail (never in practice)
        int sj = csr_src[j];
        float4 t = *(const float4*)(transformed + (sj << 5) + (c << 2));
        agg.x += t.x; agg.y += t.y; agg.z += t.z; agg.w += t.w;
    }
#pragma unroll
    for (int off = 8; off <= 32; off <<= 1) {
        agg.x += __shfl_xor(agg.x, off, 64);
        agg.y += __shfl_xor(agg.y, off, 64);
        agg.z += __shfl_xor(agg.z, off, 64);
        agg.w += __shfl_xor(agg.w, off, 64);
    }
    if (eslot == 0) {
        float al0 = 1.0f / ((float)cnt + 1e-8f);
        float4 mh;
        mh.x = fmaxf(al0 * agg.x, 0.f);
        mh.y = fmaxf(al0 * agg.y, 0.f);
        mh.z = fmaxf(al0 * agg.z, 0.f);
        mh.w = fmaxf(al0 * agg.w, 0.f);
        // mu_prev = 0: err = -mh ; mu_new = LR*mh
        float4 err = make_float4(-mh.x, -mh.y, -mh.z, -mh.w);
        float4 nm = make_float4(LR * mh.x, LR * mh.y, LR * mh.z, LR * mh.w);
        *(float4*)(mu + (n << 5) + (c << 2)) = nm;
        float4 as = *(const float4*)(a_vec + (c << 2));
        float4 ad = *(const float4*)(a_vec + OUT_F + (c << 2));
        float v1 = err.x * as.x + err.y * as.y + err.z * as.z + err.w * as.w;
        float v2 = err.x * ad.x + err.y * ad.y + err.z * ad.z + err.w * ad.w;
#pragma unroll
        for (int off = 1; off <= 4; off <<= 1) {
            v1 += __shfl_xor(v1, off, 64);
            v2 += __shfl_xor(v2, off, 64);
        }
        if (c == 0) { s_out_src[n] = v1; s_out_dst[n] = v2; }
    }
}

// Fused: softmax(alpha) in regs from s_in -> top_down -> mu update -> new s_out.
// FINAL: write alpha_csr + errors_out instead of mu/s updates.
template <bool FINAL>
__global__ __launch_bounds__(256) void fused_kernel(
        const int* __restrict__ row_start, const int* __restrict__ csr_src,
        const float* __restrict__ transformed,
        float* __restrict__ mu, float* __restrict__ errors_out,
        const float* __restrict__ a_vec,
        const float* __restrict__ s_in_src, const float* __restrict__ s_in_dst,
        float* __restrict__ s_out_src, float* __restrict__ s_out_dst,
        float* __restrict__ alpha_csr) {
    int n = blockIdx.x * 4 + (threadIdx.x >> 6);
    if (n >= N_NODES) return;
    int lane = threadIdx.x & 63;
    int eslot = lane >> 3, c = lane & 7;
    int rs = row_start[n], re = row_start[n + 1];
    float sd = s_in_dst[n];
    int idx = rs + lane;
    int my_src = (idx < re) ? csr_src[idx] : 0;
    // ---- softmax over the row (scores = leaky(s_src[src] + sd)) ----
    float sc0 = -INFINITY;
    if (idx < re) {
        float v = s_in_src[my_src] + sd;
        sc0 = v > 0.f ? v : SLOPE * v;
    }
    float m = sc0;
    for (int j2 = rs + 64 + lane; j2 < re; j2 += 64) {  // deg>64 tail
        float v = s_in_src[csr_src[j2]] + sd;
        v = v > 0.f ? v : SLOPE * v;
        m = fmaxf(m, v);
    }
#pragma unroll
    for (int off = 32; off >= 1; off >>= 1) m = fmaxf(m, __shfl_xor(m, off, 64));
    float e0 = (idx < re) ? __expf(sc0 - m) : 0.f;
    float ssum = e0;
    for (int j2 = rs + 64 + lane; j2 < re; j2 += 64) {
        float v = s_in_src[csr_src[j2]] + sd;
        v = v > 0.f ? v : SLOPE * v;
        ssum += __expf(v - m);
    }
#pragma unroll
    for (int off = 32; off >= 1; off >>= 1) ssum += __shfl_xor(ssum, off, 64);
    float inv = 1.0f / (ssum + 1e-8f);
    float my_alpha = e0 * inv;
    if (FINAL) {
        if (idx < re) alpha_csr[idx] = my_alpha;
        for (int j2 = rs + 64 + lane; j2 < re; j2 += 64) {
            float v = s_in_src[csr_src[j2]] + sd;
            v = v > 0.f ? v : SLOPE * v;
            alpha_csr[j2] = __expf(v - m) * inv;
        }
    }
    // ---- top_down with register alphas ----
    float4 agg = make_float4(0.f, 0.f, 0.f, 0.f);
#pragma unroll
    for (int k = 0; k < 8; k++) {
        int sl = eslot + 8 * k;
        float al = __shfl(my_alpha, sl, 64);
        int sj = __shfl(my_src, sl, 64);
        if (rs + sl < re) {
            float4 t = *(const float4*)(transformed + (sj << 5) + (c << 2));
            agg.x = fmaf(al, t.x, agg.x);
            agg.y = fmaf(al, t.y, agg.y);
            agg.z = fmaf(al, t.z, agg.z);
            agg.w = fmaf(al, t.w, agg.w);
        }
    }
    for (int j = rs + 64 + eslot; j < re; j += 8) {  // deg>64 tail
        int sj = csr_src[j];
        float v = s_in_src[sj] + sd;
        v = v > 0.f ? v : SLOPE * v;
        float al = __expf(v - m) * inv;
        float4 t = *(const float4*)(transformed + (sj << 5) + (c << 2));
        agg.x = fmaf(al, t.x, agg.x);
        agg.y = fmaf(al, t.y, agg.y);
        agg.z = fmaf(al, t.z, agg.z);
        agg.w = fmaf(al, t.w, agg.w);
    }
#pragma unroll
    for (int off = 8; off <= 32; off <<= 1) {
        agg.x += __shfl_xor(agg.x, off, 64);
        agg.y += __shfl_xor(agg.y, off, 64);
        agg.z += __shfl_xor(agg.z, off, 64);
        agg.w += __shfl_xor(agg.w, off, 64);
    }
    if (eslot == 0) {
        float4* mup = (float4*)(mu + (n << 5) + (c << 2));
        float4 muv = *mup;
        float4 err;
        err.x = muv.x - fmaxf(agg.x, 0.f);
        err.y = muv.y - fmaxf(agg.y, 0.f);
        err.z = muv.z - fmaxf(agg.z, 0.f);
        err.w = muv.w - fmaxf(agg.w, 0.f);
        if (FINAL) {
            *(float4*)(errors_out + (n << 5) + (c << 2)) = err;
        } else {
            float4 nm;
            nm.x = fmaf(-LR, err.x, muv.x);
            nm.y = fmaf(-LR, err.y, muv.y);
            nm.z = fmaf(-LR, err.z, muv.z);
            nm.w = fmaf(-LR, err.w, muv.w);
            *mup = nm;
            float4 as = *(const float4*)(a_vec + (c << 2));
            float4 ad = *(const float4*)(a_vec + OUT_F + (c << 2));
            float v1 = err.x * as.x + err.y * as.y + err.z * as.z + err.w * as.w;
            float v2 = err.x * ad.x + err.y * ad.y + err.z * ad.z + err.w * ad.w;
#pragma unroll
            for (int off = 1; off <= 4; off <<= 1) {
                v1 += __shfl_xor(v1, off, 64);
                v2 += __shfl_xor(v2, off, 64);
            }
            if (c == 0) { s_out_src[n] = v1; s_out_dst[n] = v2; }
        }
    }
}

// final: original-order alpha via gather through inverse permutation
__global__ void gather_alpha_kernel(const int* __restrict__ perm,
                                    const float* __restrict__ alpha_csr,
                                    float* __restrict__ alpha_out) {
    int e = blockIdx.x * blockDim.x + threadIdx.x;
    if (e < N_EDGES) alpha_out[e] = alpha_csr[perm[e]];
}

extern "C" void kernel_launch(void* const* d_in, const int* in_sizes, int n_in,
                              void* d_out, int out_size, void* d_ws, size_t ws_size,
                              hipStream_t stream) {
    const float* mu_upper = (const float*)d_in[0];
    const float* W        = (const float*)d_in[1];
    const float* a_vec    = (const float*)d_in[2];
    const int*   edge_idx = (const int*)d_in[3];
    const int*   src = edge_idx;
    const int*   dst = edge_idx + N_EDGES;

    float* out = (float*)d_out;
    float* mu         = out;                        // N*32
    float* errors_out = out + N_NODES * OUT_F;      // N*32
    float* alpha_out  = out + 2 * N_NODES * OUT_F;  // E

    char* ws = (char*)d_ws;
    int*   deg        = (int*)(ws + 0);             // 200000
    int*   row_scan   = (int*)(ws + 200000);        // 200000
    int*   row_start  = (int*)(ws + 400000);        // 200004 -> 600016
    int*   blocksum   = (int*)(ws + 600016);        // 1024   -> 601040
    int*   cursor     = (int*)(ws + 601040);        // 200000 -> 801040
    float* sA_src     = (float*)(ws + 801040);      // 200000 -> 1001040
    float* sA_dst     = (float*)(ws + 1001040);     // 200000 -> 1201040
    float* sB_src     = (float*)(ws + 1201040);     // 200000 -> 1401040
    float* sB_dst     = (float*)(ws + 1401040);     // 200000 -> 1601040
    int*   csr_src    = (int*)(ws + 1601040);       // 3200000 -> 4801040
    int*   perm       = (int*)(ws + 4801040);       // 3200000 -> 8001040
    float* alpha_csr  = (float*)(ws + 8001040);     // 3200000 -> 11201040
    float* transformed= (float*)(ws + 11201040);    // 6400000 -> 17601040 (~17.6 MB)

    hipMemsetAsync(deg, 0, N_NODES * sizeof(int), stream);
    hipMemsetAsync(cursor, 0, N_NODES * sizeof(int), stream);

    hist_kernel<<<(N_EDGES + 255) / 256, 256, 0, stream>>>(dst, deg);
    scan1_kernel<<<SCAN_NBLK, SCAN_BLK, 0, stream>>>(deg, row_scan, blocksum);
    scan2_kernel<<<1, 256, 0, stream>>>(blocksum);
    scan3_kernel<<<SCAN_NBLK, SCAN_BLK, 0, stream>>>(row_scan, blocksum, row_start);
    csr_build_kernel<<<(N_EDGES + 255) / 256, 256, 0, stream>>>(src, dst, row_start, cursor,
                                                                csr_src, perm);
    transform_kernel<<<(N_NODES + 255) / 256, 256, 0, stream>>>(mu_upper, W, transformed);

    const int NB = (N_NODES + 3) / 4;  // 4 nodes (waves) per 256-thread block
    firstA_kernel<<<NB, 256, 0, stream>>>(row_start, csr_src, transformed, mu, a_vec,
                                          sA_src, sA_dst);
    float *si_src = sA_src, *si_dst = sA_dst, *so_src = sB_src, *so_dst = sB_dst;
    for (int t = 2; t <= STEPS; t++) {  // 19 fused iterations
        fused_kernel<false><<<NB, 256, 0, stream>>>(
            row_start, csr_src, transformed, mu, errors_out, a_vec,
            si_src, si_dst, so_src, so_dst, alpha_csr);
        float* tmp;
        tmp = si_src; si_src = so_src; so_src = tmp;
        tmp = si_dst; si_dst = so_dst; so_dst = tmp;
    }
    fused_kernel<true><<<NB, 256, 0, stream>>>(
        row_start, csr_src, transformed, mu, errors_out, a_vec,
        si_src, si_dst, so_src, so_dst, alpha_csr);
    gather_alpha_kernel<<<(N_EDGES + 255) / 256, 256, 0, stream>>>(perm, alpha_csr, alpha_out);
}

// Round 6
// 768.574 us; speedup vs baseline: 1.1692x; 1.0619x over previous
//
#include <hip/hip_runtime.h>
#include <hip/hip_fp16.h>
#include <math.h>

#define N_NODES 50000
#define N_EDGES 800000
#define IN_F 64
#define OUT_F 32
#define STEPS 20
#define LR 0.1f
#define SLOPE 0.2f

#define SCAN_BLK 256
#define SCAN_NBLK ((N_NODES + SCAN_BLK - 1) / SCAN_BLK)  // 196

// ---------------- CSR build ----------------

__global__ void hist_kernel(const int* __restrict__ dst, int* __restrict__ deg) {
    int e = blockIdx.x * blockDim.x + threadIdx.x;
    if (e < N_EDGES) atomicAdd(&deg[dst[e]], 1);
}

__global__ void scan1_kernel(const int* __restrict__ deg, int* __restrict__ row_scan,
                             int* __restrict__ blocksum) {
    __shared__ int wsum[4];
    int tid = threadIdx.x, lane = tid & 63, wid = tid >> 6;
    int i = blockIdx.x * SCAN_BLK + tid;
    int v = (i < N_NODES) ? deg[i] : 0;
    int s = v;
    for (int off = 1; off < 64; off <<= 1) {
        int t = __shfl_up(s, off, 64);
        if (lane >= off) s += t;
    }
    if (lane == 63) wsum[wid] = s;
    __syncthreads();
    if (tid == 0) {
        int a = wsum[0]; wsum[0] = 0;
        int b = wsum[1]; wsum[1] = a; a += b;
        b = wsum[2]; wsum[2] = a; a += b;
        b = wsum[3]; wsum[3] = a; a += b;
        blocksum[blockIdx.x] = a;
    }
    __syncthreads();
    int incl = s + wsum[wid];
    if (i < N_NODES) row_scan[i] = incl;
}

__global__ void scan2_kernel(int* __restrict__ blocksum) {
    __shared__ int wsum[4];
    int tid = threadIdx.x, lane = tid & 63, wid = tid >> 6;
    int v = (tid < SCAN_NBLK) ? blocksum[tid] : 0;
    int s = v;
    for (int off = 1; off < 64; off <<= 1) {
        int t = __shfl_up(s, off, 64);
        if (lane >= off) s += t;
    }
    if (lane == 63) wsum[wid] = s;
    __syncthreads();
    if (tid == 0) {
        int a = wsum[0]; wsum[0] = 0;
        int b = wsum[1]; wsum[1] = a; a += b;
        b = wsum[2]; wsum[2] = a; a += b;
        b = wsum[3]; wsum[3] = a; a += b;
    }
    __syncthreads();
    int excl = s - v + wsum[wid];
    if (tid < SCAN_NBLK) blocksum[tid] = excl;
}

__global__ void scan3_kernel(const int* __restrict__ row_scan, const int* __restrict__ blockoff,
                             int* __restrict__ row_start) {
    int i = blockIdx.x * SCAN_BLK + threadIdx.x;
    if (blockIdx.x == 0 && threadIdx.x == 0) row_start[0] = 0;
    if (i < N_NODES) row_start[i + 1] = row_scan[i] + blockoff[blockIdx.x];
}

__global__ void csr_build_kernel(const int* __restrict__ src, const int* __restrict__ dst,
                                 const int* __restrict__ row_start,
                                 int* __restrict__ cursor, int* __restrict__ csr_src,
                                 int* __restrict__ perm) {
    int e = blockIdx.x * blockDim.x + threadIdx.x;
    if (e < N_EDGES) {
        int d = dst[e];
        int p = atomicAdd(&cursor[d], 1) + row_start[d];
        csr_src[p] = src[e];
        perm[e] = p;
    }
}

// transformed(fp16) = mu_upper @ W^T : thread per (node, output-pair) -> 800k threads
__global__ __launch_bounds__(256) void transform_kernel(const float* __restrict__ mu_upper,
                                                        const float* __restrict__ W,
                                                        __half* __restrict__ th) {
    int t = blockIdx.x * 256 + threadIdx.x;  // t = n*16 + op
    if (t >= N_NODES * 16) return;
    int n = t >> 4, op = t & 15;
    const float4* m4 = (const float4*)(mu_upper + n * IN_F);
    const float4* w0 = (const float4*)(W + (2 * op) * IN_F);
    const float4* w1 = (const float4*)(W + (2 * op + 1) * IN_F);
    float a0 = 0.f, a1 = 0.f;
#pragma unroll
    for (int k = 0; k < 16; k++) {
        float4 r = m4[k];
        float4 x = w0[k];
        a0 += r.x * x.x + r.y * x.y + r.z * x.z + r.w * x.w;
        float4 y = w1[k];
        a1 += r.x * y.x + r.y * y.y + r.z * y.z + r.w * y.w;
    }
    *(__half2*)(th + n * OUT_F + 2 * op) = __floats2half2_rn(a0, a1);
}

// ---------------- main iteration (fused) ----------------
// ONE WAVE PER NODE. lane = eslot(0..7)*8 + c(0..7).
// Gather: 8-lane group reads a src row as 8x8B (64B, fp16), converts, accumulates fp32.

__device__ __forceinline__ void gather_fma(const __half* __restrict__ th, int sj, int c,
                                           float al, float4& agg) {
    uint2 u = *(const uint2*)(th + (sj << 5) + (c << 2));
    __half2 h01 = *(__half2*)&u.x;
    __half2 h23 = *(__half2*)&u.y;
    float2 f01 = __half22float2(h01);
    float2 f23 = __half22float2(h23);
    agg.x = fmaf(al, f01.x, agg.x);
    agg.y = fmaf(al, f01.y, agg.y);
    agg.z = fmaf(al, f23.x, agg.z);
    agg.w = fmaf(al, f23.y, agg.w);
}

// First iteration: alpha0 = 1/(deg+eps) uniform; mu_prev = 0.
__global__ __launch_bounds__(256) void firstA_kernel(
        const int* __restrict__ row_start, const int* __restrict__ csr_src,
        const __half* __restrict__ th,
        float* __restrict__ mu, const float* __restrict__ a_vec,
        float* __restrict__ s_out_src, float* __restrict__ s_out_dst) {
    int n = blockIdx.x * 4 + (threadIdx.x >> 6);
    if (n >= N_NODES) return;
    int lane = threadIdx.x & 63;
    int eslot = lane >> 3, c = lane & 7;
    int rs = row_start[n], re = row_start[n + 1];
    int cnt = re - rs;
    int idx = rs + lane;
    int my_src = (idx < re) ? csr_src[idx] : 0;
    float4 agg = make_float4(0.f, 0.f, 0.f, 0.f);
    int kmax = cnt < 64 ? ((cnt + 7) >> 3) : 8;
    for (int k = 0; k < kmax; k++) {
        int sl = eslot + 8 * k;
        int sj = __shfl(my_src, sl, 64);
        if (rs + sl < re) gather_fma(th, sj, c, 1.0f, agg);
    }
    for (int j = rs + 64 + eslot; j < re; j += 8) {  // deg>64 tail
        gather_fma(th, csr_src[j], c, 1.0f, agg);
    }
#pragma unroll
    for (int off = 8; off <= 32; off <<= 1) {
        agg.x += __shfl_xor(agg.x, off, 64);
        agg.y += __shfl_xor(agg.y, off, 64);
        agg.z += __shfl_xor(agg.z, off, 64);
        agg.w += __shfl_xor(agg.w, off, 64);
    }
    if (eslot == 0) {
        float al0 = 1.0f / ((float)cnt + 1e-8f);
        float4 mh;
        mh.x = fmaxf(al0 * agg.x, 0.f);
        mh.y = fmaxf(al0 * agg.y, 0.f);
        mh.z = fmaxf(al0 * agg.z, 0.f);
        mh.w = fmaxf(al0 * agg.w, 0.f);
        float4 err = make_float4(-mh.x, -mh.y, -mh.z, -mh.w);
        float4 nm = make_float4(LR * mh.x, LR * mh.y, LR * mh.z, LR * mh.w);
        *(float4*)(mu + (n << 5) + (c << 2)) = nm;
        float4 as = *(const float4*)(a_vec + (c << 2));
        float4 ad = *(const float4*)(a_vec + OUT_F + (c << 2));
        float v1 = err.x * as.x + err.y * as.y + err.z * as.z + err.w * as.w;
        float v2 = err.x * ad.x + err.y * ad.y + err.z * ad.z + err.w * ad.w;
#pragma unroll
        for (int off = 1; off <= 4; off <<= 1) {
            v1 += __shfl_xor(v1, off, 64);
            v2 += __shfl_xor(v2, off, 64);
        }
        if (c == 0) { s_out_src[n] = v1; s_out_dst[n] = v2; }
    }
}

// Fused: softmax(alpha) in regs from s_in -> top_down -> mu update -> new s_out.
template <bool FINAL>
__global__ __launch_bounds__(256) void fused_kernel(
        const int* __restrict__ row_start, const int* __restrict__ csr_src,
        const __half* __restrict__ th,
        float* __restrict__ mu, float* __restrict__ errors_out,
        const float* __restrict__ a_vec,
        const float* __restrict__ s_in_src, const float* __restrict__ s_in_dst,
        float* __restrict__ s_out_src, float* __restrict__ s_out_dst,
        float* __restrict__ alpha_csr) {
    int n = blockIdx.x * 4 + (threadIdx.x >> 6);
    if (n >= N_NODES) return;
    int lane = threadIdx.x & 63;
    int eslot = lane >> 3, c = lane & 7;
    int rs = row_start[n], re = row_start[n + 1];
    int cnt = re - rs;
    float sd = s_in_dst[n];
    int idx = rs + lane;
    int my_src = (idx < re) ? csr_src[idx] : 0;
    // ---- softmax over the row (scores = leaky(s_src[src] + sd)) ----
    float sc0 = -INFINITY;
    if (idx < re) {
        float v = s_in_src[my_src] + sd;
        sc0 = v > 0.f ? v : SLOPE * v;
    }
    float m = sc0;
    for (int j2 = rs + 64 + lane; j2 < re; j2 += 64) {
        float v = s_in_src[csr_src[j2]] + sd;
        v = v > 0.f ? v : SLOPE * v;
        m = fmaxf(m, v);
    }
#pragma unroll
    for (int off = 32; off >= 1; off >>= 1) m = fmaxf(m, __shfl_xor(m, off, 64));
    float e0 = (idx < re) ? __expf(sc0 - m) : 0.f;
    float ssum = e0;
    for (int j2 = rs + 64 + lane; j2 < re; j2 += 64) {
        float v = s_in_src[csr_src[j2]] + sd;
        v = v > 0.f ? v : SLOPE * v;
        ssum += __expf(v - m);
    }
#pragma unroll
    for (int off = 32; off >= 1; off >>= 1) ssum += __shfl_xor(ssum, off, 64);
    float inv = 1.0f / (ssum + 1e-8f);
    float my_alpha = e0 * inv;
    if (FINAL) {
        if (idx < re) alpha_csr[idx] = my_alpha;
        for (int j2 = rs + 64 + lane; j2 < re; j2 += 64) {
            float v = s_in_src[csr_src[j2]] + sd;
            v = v > 0.f ? v : SLOPE * v;
            alpha_csr[j2] = __expf(v - m) * inv;
        }
    }
    // ---- top_down with register alphas ----
    float4 agg = make_float4(0.f, 0.f, 0.f, 0.f);
    int kmax = cnt < 64 ? ((cnt + 7) >> 3) : 8;
    for (int k = 0; k < kmax; k++) {
        int sl = eslot + 8 * k;
        float al = __shfl(my_alpha, sl, 64);
        int sj = __shfl(my_src, sl, 64);
        if (rs + sl < re) gather_fma(th, sj, c, al, agg);
    }
    for (int j = rs + 64 + eslot; j < re; j += 8) {  // deg>64 tail
        int sj = csr_src[j];
        float v = s_in_src[sj] + sd;
        v = v > 0.f ? v : SLOPE * v;
        float al = __expf(v - m) * inv;
        gather_fma(th, sj, c, al, agg);
    }
#pragma unroll
    for (int off = 8; off <= 32; off <<= 1) {
        agg.x += __shfl_xor(agg.x, off, 64);
        agg.y += __shfl_xor(agg.y, off, 64);
        agg.z += __shfl_xor(agg.z, off, 64);
        agg.w += __shfl_xor(agg.w, off, 64);
    }
    if (eslot == 0) {
        float4* mup = (float4*)(mu + (n << 5) + (c << 2));
        float4 muv = *mup;
        float4 err;
        err.x = muv.x - fmaxf(agg.x, 0.f);
        err.y = muv.y - fmaxf(agg.y, 0.f);
        err.z = muv.z - fmaxf(agg.z, 0.f);
        err.w = muv.w - fmaxf(agg.w, 0.f);
        if (FINAL) {
            *(float4*)(errors_out + (n << 5) + (c << 2)) = err;
        } else {
            float4 nm;
            nm.x = fmaf(-LR, err.x, muv.x);
            nm.y = fmaf(-LR, err.y, muv.y);
            nm.z = fmaf(-LR, err.z, muv.z);
            nm.w = fmaf(-LR, err.w, muv.w);
            *mup = nm;
            float4 as = *(const float4*)(a_vec + (c << 2));
            float4 ad = *(const float4*)(a_vec + OUT_F + (c << 2));
            float v1 = err.x * as.x + err.y * as.y + err.z * as.z + err.w * as.w;
            float v2 = err.x * ad.x + err.y * ad.y + err.z * ad.z + err.w * ad.w;
#pragma unroll
            for (int off = 1; off <= 4; off <<= 1) {
                v1 += __shfl_xor(v1, off, 64);
                v2 += __shfl_xor(v2, off, 64);
            }
            if (c == 0) { s_out_src[n] = v1; s_out_dst[n] = v2; }
        }
    }
}

// final: original-order alpha via gather through inverse permutation
__global__ void gather_alpha_kernel(const int* __restrict__ perm,
                                    const float* __restrict__ alpha_csr,
                                    float* __restrict__ alpha_out) {
    int e = blockIdx.x * blockDim.x + threadIdx.x;
    if (e < N_EDGES) alpha_out[e] = alpha_csr[perm[e]];
}

extern "C" void kernel_launch(void* const* d_in, const int* in_sizes, int n_in,
                              void* d_out, int out_size, void* d_ws, size_t ws_size,
                              hipStream_t stream) {
    const float* mu_upper = (const float*)d_in[0];
    const float* W        = (const float*)d_in[1];
    const float* a_vec    = (const float*)d_in[2];
    const int*   edge_idx = (const int*)d_in[3];
    const int*   src = edge_idx;
    const int*   dst = edge_idx + N_EDGES;

    float* out = (float*)d_out;
    float* mu         = out;                        // N*32
    float* errors_out = out + N_NODES * OUT_F;      // N*32
    float* alpha_out  = out + 2 * N_NODES * OUT_F;  // E

    char* ws = (char*)d_ws;
    int*   deg        = (int*)(ws + 0);             // 200000
    int*   row_scan   = (int*)(ws + 200000);        // 200000
    int*   row_start  = (int*)(ws + 400000);        // 200004 -> 600016
    int*   blocksum   = (int*)(ws + 600016);        // 1024   -> 601040
    int*   cursor     = (int*)(ws + 601040);        // 200000 -> 801040
    float* sA_src     = (float*)(ws + 801040);      // 200000 -> 1001040
    float* sA_dst     = (float*)(ws + 1001040);     // 200000 -> 1201040
    float* sB_src     = (float*)(ws + 1201040);     // 200000 -> 1401040
    float* sB_dst     = (float*)(ws + 1401040);     // 200000 -> 1601040
    int*   csr_src    = (int*)(ws + 1601040);       // 3200000 -> 4801040
    int*   perm       = (int*)(ws + 4801040);       // 3200000 -> 8001040
    float* alpha_csr  = (float*)(ws + 8001040);     // 3200000 -> 11201040
    __half* transformed_h = (__half*)(ws + 11201040); // 3200000 -> 14401040 (~14.4 MB)

    hipMemsetAsync(deg, 0, N_NODES * sizeof(int), stream);
    hipMemsetAsync(cursor, 0, N_NODES * sizeof(int), stream);

    hist_kernel<<<(N_EDGES + 255) / 256, 256, 0, stream>>>(dst, deg);
    scan1_kernel<<<SCAN_NBLK, SCAN_BLK, 0, stream>>>(deg, row_scan, blocksum);
    scan2_kernel<<<1, 256, 0, stream>>>(blocksum);
    scan3_kernel<<<SCAN_NBLK, SCAN_BLK, 0, stream>>>(row_scan, blocksum, row_start);
    csr_build_kernel<<<(N_EDGES + 255) / 256, 256, 0, stream>>>(src, dst, row_start, cursor,
                                                                csr_src, perm);
    transform_kernel<<<(N_NODES * 16 + 255) / 256, 256, 0, stream>>>(mu_upper, W, transformed_h);

    const int NB = (N_NODES + 3) / 4;  // 4 nodes (waves) per 256-thread block
    firstA_kernel<<<NB, 256, 0, stream>>>(row_start, csr_src, transformed_h, mu, a_vec,
                                          sA_src, sA_dst);
    float *si_src = sA_src, *si_dst = sA_dst, *so_src = sB_src, *so_dst = sB_dst;
    for (int t = 2; t <= STEPS; t++) {  // 19 fused iterations
        fused_kernel<false><<<NB, 256, 0, stream>>>(
            row_start, csr_src, transformed_h, mu, errors_out, a_vec,
            si_src, si_dst, so_src, so_dst, alpha_csr);
        float* tmp;
        tmp = si_src; si_src = so_src; so_src = tmp;
        tmp = si_dst; si_dst = so_dst; so_dst = tmp;
    }
    fused_kernel<true><<<NB, 256, 0, stream>>>(
        row_start, csr_src, transformed_h, mu, errors_out, a_vec,
        si_src, si_dst, so_src, so_dst, alpha_csr);
    gather_alpha_kernel<<<(N_EDGES + 255) / 256, 256, 0, stream>>>(perm, alpha_csr, alpha_out);
}

// Round 7
// 742.834 us; speedup vs baseline: 1.2097x; 1.0347x over previous
//
#include <hip/hip_runtime.h>
#include <hip/hip_fp16.h>
#include <math.h>

#define N_NODES 50000
#define N_EDGES 800000
#define IN_F 64
#define OUT_F 32
#define STEPS 20
#define LR 0.1f
#define SLOPE 0.2f

#define SCAN_BLK 256
#define SCAN_NBLK ((N_NODES + SCAN_BLK - 1) / SCAN_BLK)  // 196

// ---------------- CSR build ----------------

__global__ void hist_kernel(const int* __restrict__ dst, int* __restrict__ deg) {
    int e = blockIdx.x * blockDim.x + threadIdx.x;
    if (e < N_EDGES) atomicAdd(&deg[dst[e]], 1);
}

__global__ void scan1_kernel(const int* __restrict__ deg, int* __restrict__ row_scan,
                             int* __restrict__ blocksum) {
    __shared__ int wsum[4];
    int tid = threadIdx.x, lane = tid & 63, wid = tid >> 6;
    int i = blockIdx.x * SCAN_BLK + tid;
    int v = (i < N_NODES) ? deg[i] : 0;
    int s = v;
    for (int off = 1; off < 64; off <<= 1) {
        int t = __shfl_up(s, off, 64);
        if (lane >= off) s += t;
    }
    if (lane == 63) wsum[wid] = s;
    __syncthreads();
    if (tid == 0) {
        int a = wsum[0]; wsum[0] = 0;
        int b = wsum[1]; wsum[1] = a; a += b;
        b = wsum[2]; wsum[2] = a; a += b;
        b = wsum[3]; wsum[3] = a; a += b;
        blocksum[blockIdx.x] = a;
    }
    __syncthreads();
    int incl = s + wsum[wid];
    if (i < N_NODES) row_scan[i] = incl;
}

__global__ void scan2_kernel(int* __restrict__ blocksum) {
    __shared__ int wsum[4];
    int tid = threadIdx.x, lane = tid & 63, wid = tid >> 6;
    int v = (tid < SCAN_NBLK) ? blocksum[tid] : 0;
    int s = v;
    for (int off = 1; off < 64; off <<= 1) {
        int t = __shfl_up(s, off, 64);
        if (lane >= off) s += t;
    }
    if (lane == 63) wsum[wid] = s;
    __syncthreads();
    if (tid == 0) {
        int a = wsum[0]; wsum[0] = 0;
        int b = wsum[1]; wsum[1] = a; a += b;
        b = wsum[2]; wsum[2] = a; a += b;
        b = wsum[3]; wsum[3] = a; a += b;
    }
    __syncthreads();
    int excl = s - v + wsum[wid];
    if (tid < SCAN_NBLK) blocksum[tid] = excl;
}

__global__ void scan3_kernel(const int* __restrict__ row_scan, const int* __restrict__ blockoff,
                             int* __restrict__ row_start) {
    int i = blockIdx.x * SCAN_BLK + threadIdx.x;
    if (blockIdx.x == 0 && threadIdx.x == 0) row_start[0] = 0;
    if (i < N_NODES) row_start[i + 1] = row_scan[i] + blockoff[blockIdx.x];
}

__global__ void csr_build_kernel(const int* __restrict__ src, const int* __restrict__ dst,
                                 const int* __restrict__ row_start,
                                 int* __restrict__ cursor, int* __restrict__ csr_src,
                                 int* __restrict__ perm) {
    int e = blockIdx.x * blockDim.x + threadIdx.x;
    if (e < N_EDGES) {
        int d = dst[e];
        int p = atomicAdd(&cursor[d], 1) + row_start[d];
        csr_src[p] = src[e];
        perm[e] = p;
    }
}

// transformed(fp16) = mu_upper @ W^T : thread per (node, output-pair); W in LDS (padded)
__global__ __launch_bounds__(256) void transform_kernel(const float* __restrict__ mu_upper,
                                                        const float* __restrict__ W,
                                                        __half* __restrict__ th) {
    __shared__ float4 Ws[OUT_F][17];  // padded: op-groups land on different banks
    int tid = threadIdx.x;
    for (int t = tid; t < OUT_F * 16; t += 256) Ws[t >> 4][t & 15] = ((const float4*)W)[t];
    __syncthreads();
    int t = blockIdx.x * 256 + tid;  // t = n*16 + op
    if (t >= N_NODES * 16) return;
    int n = t >> 4, op = t & 15;
    const float4* m4 = (const float4*)(mu_upper + n * IN_F);
    float a0 = 0.f, a1 = 0.f;
#pragma unroll
    for (int k = 0; k < 16; k++) {
        float4 r = m4[k];
        float4 x = Ws[2 * op][k];
        a0 += r.x * x.x + r.y * x.y + r.z * x.z + r.w * x.w;
        float4 y = Ws[2 * op + 1][k];
        a1 += r.x * y.x + r.y * y.y + r.z * y.z + r.w * y.w;
    }
    *(__half2*)(th + n * OUT_F + 2 * op) = __floats2half2_rn(a0, a1);
}

// one-time: pack T rows into CSR-slot order (sequential per-iter streams)
__global__ void pack_kernel(const int* __restrict__ csr_src, const __half* __restrict__ th,
                            __half* __restrict__ Tpack) {
    int t = blockIdx.x * 256 + threadIdx.x;  // t = slot*8 + c
    if (t >= N_EDGES * 8) return;
    int slot = t >> 3, c = t & 7;
    int sj = csr_src[slot];
    *(uint2*)(Tpack + (slot << 5) + (c << 2)) = *(const uint2*)(th + (sj << 5) + (c << 2));
}

// ---------------- main iteration (fused) ----------------
// ONE WAVE PER NODE. lane = eslot(0..7)*8 + c(0..7).

__device__ __forceinline__ void fma_h8(uint2 u, float al, float4& agg) {
    float2 f01 = __half22float2(*(__half2*)&u.x);
    float2 f23 = __half22float2(*(__half2*)&u.y);
    agg.x = fmaf(al, f01.x, agg.x);
    agg.y = fmaf(al, f01.y, agg.y);
    agg.z = fmaf(al, f23.x, agg.z);
    agg.w = fmaf(al, f23.y, agg.w);
}

// First iteration: alpha0 = 1/(deg+eps) uniform; mu_prev = 0.
template <bool PACKED>
__global__ __launch_bounds__(256) void firstA_kernel(
        const int* __restrict__ row_start, const int* __restrict__ csr_src,
        const __half* __restrict__ th, const __half* __restrict__ Tpack,
        float* __restrict__ mu, const float* __restrict__ a_vec,
        float* __restrict__ s_out_src, float* __restrict__ s_out_dst) {
    int n = blockIdx.x * 4 + (threadIdx.x >> 6);
    if (n >= N_NODES) return;
    int lane = threadIdx.x & 63;
    int eslot = lane >> 3, c = lane & 7;
    int rs = row_start[n], re = row_start[n + 1];
    int cnt = re - rs;
    float4 agg = make_float4(0.f, 0.f, 0.f, 0.f);
    if (PACKED) {
        for (int j = rs + eslot; j < re; j += 8) {
            uint2 u = *(const uint2*)(Tpack + (j << 5) + (c << 2));
            fma_h8(u, 1.0f, agg);
        }
    } else {
        int idx = rs + lane;
        int my_src = (idx < re) ? csr_src[idx] : 0;
        int kmax = cnt < 64 ? ((cnt + 7) >> 3) : 8;
        for (int k = 0; k < kmax; k++) {
            int sl = eslot + 8 * k;
            int sj = __shfl(my_src, sl, 64);
            if (rs + sl < re) {
                uint2 u = *(const uint2*)(th + (sj << 5) + (c << 2));
                fma_h8(u, 1.0f, agg);
            }
        }
        for (int j = rs + 64 + eslot; j < re; j += 8) {
            uint2 u = *(const uint2*)(th + (csr_src[j] << 5) + (c << 2));
            fma_h8(u, 1.0f, agg);
        }
    }
#pragma unroll
    for (int off = 8; off <= 32; off <<= 1) {
        agg.x += __shfl_xor(agg.x, off, 64);
        agg.y += __shfl_xor(agg.y, off, 64);
        agg.z += __shfl_xor(agg.z, off, 64);
        agg.w += __shfl_xor(agg.w, off, 64);
    }
    if (eslot == 0) {
        float al0 = 1.0f / ((float)cnt + 1e-8f);
        float4 mh;
        mh.x = fmaxf(al0 * agg.x, 0.f);
        mh.y = fmaxf(al0 * agg.y, 0.f);
        mh.z = fmaxf(al0 * agg.z, 0.f);
        mh.w = fmaxf(al0 * agg.w, 0.f);
        float4 err = make_float4(-mh.x, -mh.y, -mh.z, -mh.w);
        float4 nm = make_float4(LR * mh.x, LR * mh.y, LR * mh.z, LR * mh.w);
        *(float4*)(mu + (n << 5) + (c << 2)) = nm;
        float4 as = *(const float4*)(a_vec + (c << 2));
        float4 ad = *(const float4*)(a_vec + OUT_F + (c << 2));
        float v1 = err.x * as.x + err.y * as.y + err.z * as.z + err.w * as.w;
        float v2 = err.x * ad.x + err.y * ad.y + err.z * ad.z + err.w * ad.w;
#pragma unroll
        for (int off = 1; off <= 4; off <<= 1) {
            v1 += __shfl_xor(v1, off, 64);
            v2 += __shfl_xor(v2, off, 64);
        }
        if (c == 0) { s_out_src[n] = v1; s_out_dst[n] = v2; }
    }
}

// Fused: softmax(alpha) in regs from s_in -> top_down -> mu update -> new s_out.
template <bool FINAL, bool PACKED>
__global__ __launch_bounds__(256) void fused_kernel(
        const int* __restrict__ row_start, const int* __restrict__ csr_src,
        const __half* __restrict__ th, const __half* __restrict__ Tpack,
        float* __restrict__ mu, float* __restrict__ errors_out,
        const float* __restrict__ a_vec,
        const float* __restrict__ s_in_src, const float* __restrict__ s_in_dst,
        float* __restrict__ s_out_src, float* __restrict__ s_out_dst,
        float* __restrict__ alpha_csr) {
    int n = blockIdx.x * 4 + (threadIdx.x >> 6);
    if (n >= N_NODES) return;
    int lane = threadIdx.x & 63;
    int eslot = lane >> 3, c = lane & 7;
    int rs = row_start[n], re = row_start[n + 1];
    int cnt = re - rs;
    float sd = s_in_dst[n];
    int idx = rs + lane;
    int my_src = (idx < re) ? csr_src[idx] : 0;
    // ---- softmax over the row (scores = leaky(s_src[src] + sd)) ----
    float sc0 = -INFINITY;
    if (idx < re) {
        float v = s_in_src[my_src] + sd;
        sc0 = v > 0.f ? v : SLOPE * v;
    }
    float m = sc0;
    for (int j2 = rs + 64 + lane; j2 < re; j2 += 64) {
        float v = s_in_src[csr_src[j2]] + sd;
        v = v > 0.f ? v : SLOPE * v;
        m = fmaxf(m, v);
    }
#pragma unroll
    for (int off = 32; off >= 1; off >>= 1) m = fmaxf(m, __shfl_xor(m, off, 64));
    float e0 = (idx < re) ? __expf(sc0 - m) : 0.f;
    float ssum = e0;
    for (int j2 = rs + 64 + lane; j2 < re; j2 += 64) {
        float v = s_in_src[csr_src[j2]] + sd;
        v = v > 0.f ? v : SLOPE * v;
        ssum += __expf(v - m);
    }
#pragma unroll
    for (int off = 32; off >= 1; off >>= 1) ssum += __shfl_xor(ssum, off, 64);
    float inv = 1.0f / (ssum + 1e-8f);
    float my_alpha = e0 * inv;
    if (FINAL) {
        if (idx < re) alpha_csr[idx] = my_alpha;
        for (int j2 = rs + 64 + lane; j2 < re; j2 += 64) {
            float v = s_in_src[csr_src[j2]] + sd;
            v = v > 0.f ? v : SLOPE * v;
            alpha_csr[j2] = __expf(v - m) * inv;
        }
    }
    // ---- top_down ----
    float4 agg = make_float4(0.f, 0.f, 0.f, 0.f);
    int kmax = cnt < 64 ? ((cnt + 7) >> 3) : 8;
    for (int k = 0; k < kmax; k++) {
        int sl = eslot + 8 * k;
        float al = __shfl(my_alpha, sl, 64);
        if (rs + sl < re) {
            uint2 u;
            if (PACKED) u = *(const uint2*)(Tpack + ((rs + sl) << 5) + (c << 2));
            else {
                int sj = __shfl(my_src, sl, 64);
                u = *(const uint2*)(th + (sj << 5) + (c << 2));
            }
            fma_h8(u, al, agg);
        }
    }
    for (int j = rs + 64 + eslot; j < re; j += 8) {  // deg>64 tail
        int sj = csr_src[j];
        float v = s_in_src[sj] + sd;
        v = v > 0.f ? v : SLOPE * v;
        float al = __expf(v - m) * inv;
        uint2 u;
        if (PACKED) u = *(const uint2*)(Tpack + (j << 5) + (c << 2));
        else u = *(const uint2*)(th + (sj << 5) + (c << 2));
        fma_h8(u, al, agg);
    }
#pragma unroll
    for (int off = 8; off <= 32; off <<= 1) {
        agg.x += __shfl_xor(agg.x, off, 64);
        agg.y += __shfl_xor(agg.y, off, 64);
        agg.z += __shfl_xor(agg.z, off, 64);
        agg.w += __shfl_xor(agg.w, off, 64);
    }
    if (eslot == 0) {
        float4* mup = (float4*)(mu + (n << 5) + (c << 2));
        float4 muv = *mup;
        float4 err;
        err.x = muv.x - fmaxf(agg.x, 0.f);
        err.y = muv.y - fmaxf(agg.y, 0.f);
        err.z = muv.z - fmaxf(agg.z, 0.f);
        err.w = muv.w - fmaxf(agg.w, 0.f);
        if (FINAL) {
            *(float4*)(errors_out + (n << 5) + (c << 2)) = err;
        } else {
            float4 nm;
            nm.x = fmaf(-LR, err.x, muv.x);
            nm.y = fmaf(-LR, err.y, muv.y);
            nm.z = fmaf(-LR, err.z, muv.z);
            nm.w = fmaf(-LR, err.w, muv.w);
            *mup = nm;
            float4 as = *(const float4*)(a_vec + (c << 2));
            float4 ad = *(const float4*)(a_vec + OUT_F + (c << 2));
            float v1 = err.x * as.x + err.y * as.y + err.z * as.z + err.w * as.w;
            float v2 = err.x * ad.x + err.y * ad.y + err.z * ad.z + err.w * ad.w;
#pragma unroll
            for (int off = 1; off <= 4; off <<= 1) {
                v1 += __shfl_xor(v1, off, 64);
                v2 += __shfl_xor(v2, off, 64);
            }
            if (c == 0) { s_out_src[n] = v1; s_out_dst[n] = v2; }
        }
    }
}

// final: original-order alpha via gather through inverse permutation
__global__ void gather_alpha_kernel(const int* __restrict__ perm,
                                    const float* __restrict__ alpha_csr,
                                    float* __restrict__ alpha_out) {
    int e = blockIdx.x * blockDim.x + threadIdx.x;
    if (e < N_EDGES) alpha_out[e] = alpha_csr[perm[e]];
}

extern "C" void kernel_launch(void* const* d_in, const int* in_sizes, int n_in,
                              void* d_out, int out_size, void* d_ws, size_t ws_size,
                              hipStream_t stream) {
    const float* mu_upper = (const float*)d_in[0];
    const float* W        = (const float*)d_in[1];
    const float* a_vec    = (const float*)d_in[2];
    const int*   edge_idx = (const int*)d_in[3];
    const int*   src = edge_idx;
    const int*   dst = edge_idx + N_EDGES;

    float* out = (float*)d_out;
    float* mu         = out;
    float* errors_out = out + N_NODES * OUT_F;
    float* alpha_out  = out + 2 * N_NODES * OUT_F;

    char* ws = (char*)d_ws;
    int*   deg        = (int*)(ws + 0);
    int*   row_scan   = (int*)(ws + 200000);
    int*   row_start  = (int*)(ws + 400000);
    int*   blocksum   = (int*)(ws + 600064);
    int*   cursor     = (int*)(ws + 601088);
    float* sA_src     = (float*)(ws + 801088);
    float* sA_dst     = (float*)(ws + 1001088);
    float* sB_src     = (float*)(ws + 1201088);
    float* sB_dst     = (float*)(ws + 1401088);
    int*   csr_src    = (int*)(ws + 1601088);
    int*   perm       = (int*)(ws + 4801088);
    float* alpha_csr  = (float*)(ws + 8001088);
    __half* th        = (__half*)(ws + 11201088);   // 3.2 MB -> 14401088
    __half* Tpack     = (__half*)(ws + 14401152);   // 51.2 MB -> 65601152
    const size_t NEED_PACKED = 65601152;
    const bool packed = (ws_size >= NEED_PACKED);   // constant across calls: graph-safe

    hipMemsetAsync(deg, 0, N_NODES * sizeof(int), stream);
    hipMemsetAsync(cursor, 0, N_NODES * sizeof(int), stream);

    hist_kernel<<<(N_EDGES + 255) / 256, 256, 0, stream>>>(dst, deg);
    scan1_kernel<<<SCAN_NBLK, SCAN_BLK, 0, stream>>>(deg, row_scan, blocksum);
    scan2_kernel<<<1, 256, 0, stream>>>(blocksum);
    scan3_kernel<<<SCAN_NBLK, SCAN_BLK, 0, stream>>>(row_scan, blocksum, row_start);
    csr_build_kernel<<<(N_EDGES + 255) / 256, 256, 0, stream>>>(src, dst, row_start, cursor,
                                                                csr_src, perm);
    transform_kernel<<<(N_NODES * 16 + 255) / 256, 256, 0, stream>>>(mu_upper, W, th);
    if (packed)
        pack_kernel<<<(N_EDGES * 8 + 255) / 256, 256, 0, stream>>>(csr_src, th, Tpack);

    const int NB = (N_NODES + 3) / 4;
    float *si_src = sA_src, *si_dst = sA_dst, *so_src = sB_src, *so_dst = sB_dst;
    if (packed) {
        firstA_kernel<true><<<NB, 256, 0, stream>>>(row_start, csr_src, th, Tpack, mu, a_vec,
                                                    sA_src, sA_dst);
        for (int t = 2; t <= STEPS; t++) {
            fused_kernel<false, true><<<NB, 256, 0, stream>>>(
                row_start, csr_src, th, Tpack, mu, errors_out, a_vec,
                si_src, si_dst, so_src, so_dst, alpha_csr);
            float* tmp;
            tmp = si_src; si_src = so_src; so_src = tmp;
            tmp = si_dst; si_dst = so_dst; so_dst = tmp;
        }
        fused_kernel<true, true><<<NB, 256, 0, stream>>>(
            row_start, csr_src, th, Tpack, mu, errors_out, a_vec,
            si_src, si_dst, so_src, so_dst, alpha_csr);
    } else {
        firstA_kernel<false><<<NB, 256, 0, stream>>>(row_start, csr_src, th, Tpack, mu, a_vec,
                                                     sA_src, sA_dst);
        for (int t = 2; t <= STEPS; t++) {
            fused_kernel<false, false><<<NB, 256, 0, stream>>>(
                row_start, csr_src, th, Tpack, mu, errors_out, a_vec,
                si_src, si_dst, so_src, so_dst, alpha_csr);
            float* tmp;
            tmp = si_src; si_src = so_src; so_src = tmp;
            tmp = si_dst; si_dst = so_dst; so_dst = tmp;
        }
        fused_kernel<true, false><<<NB, 256, 0, stream>>>(
            row_start, csr_src, th, Tpack, mu, errors_out, a_vec,
            si_src, si_dst, so_src, so_dst, alpha_csr);
    }
    gather_alpha_kernel<<<(N_EDGES + 255) / 256, 256, 0, stream>>>(perm, alpha_csr, alpha_out);
}